// Round 1
// baseline (45.421 us; speedup 1.0000x reference)
//
#include <hip/hip_runtime.h>
#include <math.h>

#define NROWS 8192
#define NCOLS 4096
#define RPC 64                     // rows per chunk
#define NCHUNK (NROWS / RPC)       // 128
#define TPB 256
#define CPT 4                      // cols per thread (float4)
#define CTILE (TPB * CPT)          // 1024
#define NTILE (NCOLS / CTILE)      // 4

// Stage 1: per-(chunk, column) partial tss and colsum in double.
__global__ __launch_bounds__(TPB) void tss_partial_kernel(
    const float* __restrict__ x,
    double* __restrict__ ptss,
    double* __restrict__ pcs)
{
    const int tid   = threadIdx.x;
    const int tile  = blockIdx.x;   // 0..NTILE-1
    const int chunk = blockIdx.y;   // 0..NCHUNK-1
    const int col   = tile * CTILE + tid * CPT;
    const int r0    = chunk * RPC;

    __shared__ float  x0[RPC + 1];
    __shared__ double da_sh[RPC];

    // column-0 values for rows r0..r0+RPC (strided loads, tiny volume)
    if (tid <= RPC) {
        int r = r0 + tid;
        x0[tid] = (r < NROWS) ? x[(size_t)r * NCOLS] : 0.0f;
    }
    __syncthreads();
    if (tid < RPC) {
        da_sh[tid] = (double)x0[tid + 1] - (double)x0[tid];
    }
    __syncthreads();

    const float4* row = (const float4*)(x + (size_t)r0 * NCOLS + col);
    const int rs = NCOLS / 4;       // row stride in float4

    // number of valid diff indices in this chunk (64, or 63 for last chunk)
    const int ND = min(RPC, (NROWS - 1) - r0);

    double tss0 = 0.0, tss1 = 0.0, tss2 = 0.0, tss3 = 0.0;
    double cs0 = 0.0, cs1 = 0.0, cs2 = 0.0, cs3 = 0.0;

    float4 cur = row[0];            // row r0
    float4 nxt = row[rs];           // row r0+1 (always exists: r0+1 <= 8129)

    for (int i = 0; i < RPC; ++i) {
        // prefetch row r0+i+2 (2-deep pipeline)
        float4 pf = nxt;
        const bool havepf = (i + 2 <= RPC) && (r0 + i + 2 < NROWS);
        if (havepf) pf = row[(i + 2) * rs];

        // colsum contribution of row r0+i
        cs0 += (double)cur.x; cs1 += (double)cur.y;
        cs2 += (double)cur.z; cs3 += (double)cur.w;

        if (i < ND) {
            const double da = da_sh[i];
            double db, df;
            db = (double)nxt.x - (double)cur.x; df = da - db;
            tss0 += (da * db >= 0.0) ? df : fabs(df);
            db = (double)nxt.y - (double)cur.y; df = da - db;
            tss1 += (da * db >= 0.0) ? df : fabs(df);
            db = (double)nxt.z - (double)cur.z; df = da - db;
            tss2 += (da * db >= 0.0) ? df : fabs(df);
            db = (double)nxt.w - (double)cur.w; df = da - db;
            tss3 += (da * db >= 0.0) ? df : fabs(df);
        }
        cur = nxt;
        nxt = pf;
    }

    double* pt = ptss + (size_t)chunk * NCOLS + col;
    double* pc = pcs  + (size_t)chunk * NCOLS + col;
    pt[0] = tss0; pt[1] = tss1; pt[2] = tss2; pt[3] = tss3;
    pc[0] = cs0;  pc[1] = cs1;  pc[2] = cs2;  pc[3] = cs3;
}

// Stage 2: per-column reduce over chunks + score/tan epilogue.
__global__ __launch_bounds__(256) void tss_finalize_kernel(
    const double* __restrict__ ptss,
    const double* __restrict__ pcs,
    const float* __restrict__ variance,
    double* __restrict__ t_arr,
    double* __restrict__ tc_arr)
{
    const int j = blockIdx.x * blockDim.x + threadIdx.x;  // 0..NCOLS-1
    double tss = 0.0, cs = 0.0;
    for (int c = 0; c < NCHUNK; ++c) {
        tss += ptss[(size_t)c * NCOLS + j];
        cs  += pcs[(size_t)c * NCOLS + j];
    }
    double t = 0.0, tc = 0.0;
    if (j >= 1) {
        const double var = (double)variance[0];
        const double SQRT_2PI = 2.5066282746310005024;
        const double coef = 1.0 / (SQRT_2PI * var);
        const double score = coef * exp(-(tss * tss) / (2.0 * var * var));
        t  = tan(score);
        tc = t * cs;
    }
    t_arr[j]  = t;
    tc_arr[j] = tc;
}

// Stage 3: final scalar.
__global__ __launch_bounds__(1024) void tss_reduce_kernel(
    const double* __restrict__ t_arr,
    const double* __restrict__ tc_arr,
    float* __restrict__ out)
{
    const int tid = threadIdx.x;
    double st = 0.0, stc = 0.0;
    for (int j = tid; j < NCOLS; j += 1024) {
        st  += t_arr[j];
        stc += tc_arr[j];
    }
    __shared__ double s1[1024];
    __shared__ double s2[1024];
    s1[tid] = st; s2[tid] = stc;
    __syncthreads();
    for (int s = 512; s > 0; s >>= 1) {
        if (tid < s) { s1[tid] += s1[tid + s]; s2[tid] += s2[tid + s]; }
        __syncthreads();
    }
    if (tid == 0) out[0] = (float)(s2[0] / s1[0]);
}

extern "C" void kernel_launch(void* const* d_in, const int* in_sizes, int n_in,
                              void* d_out, int out_size, void* d_ws, size_t ws_size,
                              hipStream_t stream) {
    const float* x   = (const float*)d_in[0];
    const float* var = (const float*)d_in[1];
    float* out = (float*)d_out;

    double* ws     = (double*)d_ws;
    double* ptss   = ws;                                   // NCHUNK*NCOLS doubles (4 MiB)
    double* pcs    = ptss + (size_t)NCHUNK * NCOLS;        // NCHUNK*NCOLS doubles (4 MiB)
    double* t_arr  = pcs + (size_t)NCHUNK * NCOLS;         // NCOLS doubles
    double* tc_arr = t_arr + NCOLS;                        // NCOLS doubles

    dim3 g1(NTILE, NCHUNK);
    tss_partial_kernel<<<g1, TPB, 0, stream>>>(x, ptss, pcs);
    tss_finalize_kernel<<<NCOLS / 256, 256, 0, stream>>>(ptss, pcs, var, t_arr, tc_arr);
    tss_reduce_kernel<<<1, 1024, 0, stream>>>(t_arr, tc_arr, out);
}